// Round 4
// baseline (796.431 us; speedup 1.0000x reference)
//
#include <hip/hip_runtime.h>
#include <stdint.h>

// SparseLinear: out[m][n] = sum_k x[m][k] * W[n][k] * mask[n][k]
// M = B*S = 8192, N = 4096, K = 4096, fp32 in/out, bf16-tolerance check.
// R3: k-major LDS panel layout (slot = chunk*32 + row within 32-row panels)
// -> fragment ds_reads are lane-contiguous (m134's conflict-free pattern),
// killing R2's structural 4-way conflicts (3.35e7 extra cycles ~ 20% wall).
// Staging global pattern becomes 2 cols x 32 rows x 16 B per wave (scattered,
// same bytes). Linear block order restored (R2 swizzle raised fetch 328->530MB).
// Pre-passes: fused memset+detect (1 block), 16-elem/thread converters.

static constexpr int Mdim = 8192;
static constexpr int Ndim = 4096;
static constexpr int Kdim = 4096;
static constexpr int BM = 128;
static constexpr int BN = 128;
static constexpr int BK = 64;

typedef __attribute__((ext_vector_type(8))) short short8;
typedef __attribute__((ext_vector_type(4))) float float4v;
typedef __attribute__((ext_vector_type(16))) float float16v;
typedef __attribute__((ext_vector_type(4))) int int4v;
typedef __attribute__((ext_vector_type(4))) unsigned int uint4v;
typedef __attribute__((ext_vector_type(8))) unsigned short ushort8;

__device__ __forceinline__ unsigned short f32_to_bf16(float f) {
  union { float f; uint32_t u; } c; c.f = f;
  uint32_t u = c.u;
  u += 0x7fffu + ((u >> 16) & 1u);   // round-to-nearest-even (no NaNs in data)
  return (unsigned short)(u >> 16);
}

// ---------------------------------------------------------------------------
// Mask element-width detection (fused flag init). numpy bool_ = 1 byte;
// int32/float32 promotion zeroes byte positions ==1 (mod 4). Scanning 64K
// positions at 10% density: P(miss) = 0.9^65536 ~ 0.
// ---------------------------------------------------------------------------
__global__ void detect_mask_kernel(const unsigned char* __restrict__ m, int* __restrict__ flag) {
  __shared__ int s;
  if (threadIdx.x == 0) s = 0;
  __syncthreads();
  int found = 0;
  for (int p = threadIdx.x; p < 65536; p += blockDim.x)
    found |= (m[4 * p + 1] != 0);
  if (found) atomicOr(&s, 1);
  __syncthreads();
  if (threadIdx.x == 0) *flag = s;
}

// x fp32 -> bf16, 16 elements/thread
__global__ void cvt_x_kernel(const float* __restrict__ x, unsigned short* __restrict__ o) {
  long i = (blockIdx.x * (long)blockDim.x + threadIdx.x) * 16;
  float4v v[4];
#pragma unroll
  for (int t = 0; t < 4; ++t) v[t] = *(const float4v*)(x + i + 4 * t);
  ushort8 r0, r1;
#pragma unroll
  for (int t = 0; t < 4; ++t) r0[t] = f32_to_bf16(v[0][t]);
#pragma unroll
  for (int t = 0; t < 4; ++t) r0[4 + t] = f32_to_bf16(v[1][t]);
#pragma unroll
  for (int t = 0; t < 4; ++t) r1[t] = f32_to_bf16(v[2][t]);
#pragma unroll
  for (int t = 0; t < 4; ++t) r1[4 + t] = f32_to_bf16(v[3][t]);
  *(ushort8*)(o + i) = r0;
  *(ushort8*)(o + i + 8) = r1;
}

// W fp32 * mask -> bf16, 16 elements/thread; mask layout chosen by *flag
__global__ void cvt_w_kernel(const float* __restrict__ w, const unsigned char* __restrict__ mraw,
                             const int* __restrict__ flag, unsigned short* __restrict__ o) {
  long i = (blockIdx.x * (long)blockDim.x + threadIdx.x) * 16;
  float4v v[4];
#pragma unroll
  for (int t = 0; t < 4; ++t) v[t] = *(const float4v*)(w + i + 4 * t);
  int m[16];
  if (*flag) {  // 1-byte elements: 16 mask bytes = one dwordx4
    uint4v mb = *(const uint4v*)(mraw + i);
#pragma unroll
    for (int t = 0; t < 4; ++t)
#pragma unroll
      for (int j = 0; j < 4; ++j) m[4 * t + j] = ((mb[t] >> (8 * j)) & 0xffu) != 0;
  } else {      // 4-byte elements (int32 0/1 or float32 0.0/1.0)
#pragma unroll
    for (int t = 0; t < 4; ++t) {
      int4v mv = *(const int4v*)((const int*)mraw + i + 4 * t);
#pragma unroll
      for (int j = 0; j < 4; ++j) m[4 * t + j] = mv[j] != 0;
    }
  }
  ushort8 r0, r1;
#pragma unroll
  for (int t = 0; t < 8; ++t) r0[t] = f32_to_bf16(m[t] ? v[t >> 2][t & 3] : 0.0f);
#pragma unroll
  for (int t = 0; t < 8; ++t) r1[t] = f32_to_bf16(m[8 + t] ? v[2 + (t >> 2)][t & 3] : 0.0f);
  *(ushort8*)(o + i) = r0;
  *(ushort8*)(o + i + 8) = r1;
}

// ---------------------------------------------------------------------------
// bf16 MFMA GEMM, B^T form: O[m][n] = sum_k X[m][k]*W[n][k].
// 256 threads = 4 waves in 2x2; each wave computes 64x64 as 2x2 of 32x32x16.
// A/B fragment layout (HW-validated in R2): m/n = lane&31, k = (lane>>5)*8+i.
// C/D layout (m74/m101): col = lane&31, row = (reg&3) + 8*(reg>>2) + 4*(lane>>5).
// LDS layout: 4 panels of 32 rows; within a panel, slot = chunk_col*32 + row
// (chunk = 16 B). Fragment read address = panel*4096 + s*1024 + lane*16 bytes
// -> lane-contiguous 1024 B per wave per read: conflict-free (m134 pattern),
// single address VGPR + immediate ds offsets.
// Staging (global_load_lds w=16, dest must be lane-contiguous): instruction r
// stages panel r: lane tid reads row r*32+(tid&31), col-chunk tid>>5.
// ---------------------------------------------------------------------------
__global__ __launch_bounds__(256) void gemm_bt_kernel(const unsigned short* __restrict__ X,
                                                      const unsigned short* __restrict__ W,
                                                      float* __restrict__ O) {
  __shared__ short sA[BM * BK];  // 16 KiB
  __shared__ short sB[BN * BK];  // 16 KiB

  const int tid = threadIdx.x;
  const int lane = tid & 63;
  const int wave = tid >> 6;
  const int wr = wave >> 1;   // 0..1: which 64-row half
  const int wc = wave & 1;    // 0..1: which 64-col half

  const int tm = blockIdx.x >> 5;      // linear order (R1-style; best fetch)
  const int tn = blockIdx.x & 31;
  const int row0 = tm * BM;
  const int col0 = tn * BN;

  float16v acc[2][2];
#pragma unroll
  for (int i = 0; i < 2; ++i)
#pragma unroll
    for (int j = 0; j < 2; ++j)
#pragma unroll
      for (int r = 0; r < 16; ++r) acc[i][j][r] = 0.f;

  // Staging source coords: instruction r covers panel r (rows r*32..r*32+31)
  const int st_row = tid & 31;        // row within panel
  const int st_col = (tid >> 5) * 8;  // element offset of 16B col-chunk

  const int ml = lane & 31;
  const int kg = lane >> 5;

  // All fragment reads: sA/sB byte address = lane*16 + imm(panel, s)
  const short* aBase = sA + lane * 8;   // *2 B = lane*16 bytes
  const short* bBase = sB + lane * 8;

  for (int kt = 0; kt < Kdim; kt += BK) {
#pragma unroll
    for (int r = 0; r < 4; ++r) {
      const unsigned short* gA = X + (long)(row0 + r * 32 + st_row) * Kdim + kt + st_col;
      const unsigned short* gB = W + (long)(col0 + r * 32 + st_row) * Kdim + kt + st_col;
      const int loff = (r * 256 + tid) * 16;
      __builtin_amdgcn_global_load_lds((const __attribute__((address_space(1))) void*)gA,
                                       (__attribute__((address_space(3))) void*)((char*)sA + loff),
                                       16, 0, 0);
      __builtin_amdgcn_global_load_lds((const __attribute__((address_space(1))) void*)gB,
                                       (__attribute__((address_space(3))) void*)((char*)sB + loff),
                                       16, 0, 0);
    }
    __syncthreads();

#pragma unroll
    for (int s = 0; s < 4; ++s) {                 // four 16-wide K steps
      short8 a[2], b[2];
#pragma unroll
      for (int i = 0; i < 2; ++i)
        a[i] = *(const short8*)(aBase + (wr * 2 + i) * 2048 + s * 512);
#pragma unroll
      for (int j = 0; j < 2; ++j)
        b[j] = *(const short8*)(bBase + (wc * 2 + j) * 2048 + s * 512);
#pragma unroll
      for (int i = 0; i < 2; ++i)
#pragma unroll
        for (int j = 0; j < 2; ++j)
          acc[i][j] = __builtin_amdgcn_mfma_f32_32x32x16_bf16(a[i], b[j], acc[i][j], 0, 0, 0);
    }
    __syncthreads();
  }

  // C/D layout (verified m74/m101): col = lane&31,
  // row = (reg&3) + 8*(reg>>2) + 4*(lane>>5)
#pragma unroll
  for (int i = 0; i < 2; ++i) {
#pragma unroll
    for (int j = 0; j < 2; ++j) {
      const long rbase = row0 + wr * 64 + i * 32;
      const long cg = col0 + wc * 64 + j * 32 + ml;
#pragma unroll
      for (int reg = 0; reg < 16; ++reg) {
        const long row = rbase + (reg & 3) + 8 * (reg >> 2) + 4 * kg;
        O[row * (long)Ndim + cg] = acc[i][j][reg];
      }
    }
  }
}

// ---------------------------------------------------------------------------
// Fallback (only if ws too small for bf16 staging): fp32 LDS-tiled GEMM.
// ---------------------------------------------------------------------------
__global__ void gemm_fallback_kernel(const float* __restrict__ X, const float* __restrict__ Wt,
                                     const unsigned char* __restrict__ mraw,
                                     const int* __restrict__ flag, float* __restrict__ O) {
  __shared__ float sX[16][17];
  __shared__ float sW[16][17];
  const int tx = threadIdx.x & 15;
  const int ty = threadIdx.x >> 4;
  const long row = blockIdx.y * 16 + ty;
  const long colblock = blockIdx.x * 16;
  const int byteLayout = *flag;
  float acc = 0.f;
  for (int k0 = 0; k0 < Kdim; k0 += 16) {
    sX[ty][tx] = X[row * Kdim + k0 + tx];
    const long wi = (colblock + ty) * (long)Kdim + k0 + tx;
    const int mv = byteLayout ? (mraw[wi] != 0) : (((const int*)mraw)[wi] != 0);
    sW[ty][tx] = mv ? Wt[wi] : 0.f;
    __syncthreads();
#pragma unroll
    for (int k = 0; k < 16; ++k) acc += sX[ty][k] * sW[tx][k];
    __syncthreads();
  }
  O[row * Ndim + colblock + tx] = acc;
}

extern "C" void kernel_launch(void* const* d_in, const int* in_sizes, int n_in,
                              void* d_out, int out_size, void* d_ws, size_t ws_size,
                              hipStream_t stream) {
  const float* x = (const float*)d_in[0];               // [8192, 4096] fp32
  const float* w = (const float*)d_in[1];               // [4096, 4096] fp32
  const unsigned char* mask = (const unsigned char*)d_in[2];  // bool (layout detected)
  float* out = (float*)d_out;                           // [8192, 4096] fp32

  const size_t xb_off = 0;
  const size_t wb_off = (size_t)Mdim * Kdim * 2;             // 67,108,864
  const size_t flag_off = wb_off + (size_t)Ndim * Kdim * 2;  // 100,663,296
  const size_t needed = flag_off + 16;

  if (ws_size >= needed) {
    unsigned short* xb = (unsigned short*)((char*)d_ws + xb_off);
    unsigned short* wb = (unsigned short*)((char*)d_ws + wb_off);
    int* flag = (int*)((char*)d_ws + flag_off);

    detect_mask_kernel<<<1, 1024, 0, stream>>>(mask, flag);
    cvt_x_kernel<<<(int)(((long)Mdim * Kdim / 16) / 256), 256, 0, stream>>>(x, xb);
    cvt_w_kernel<<<(int)(((long)Ndim * Kdim / 16) / 256), 256, 0, stream>>>(w, mask, flag, wb);
    gemm_bt_kernel<<<(Mdim / BM) * (Ndim / BN), 256, 0, stream>>>(xb, wb, out);
  } else {
    int* flag = (int*)d_ws;
    detect_mask_kernel<<<1, 1024, 0, stream>>>(mask, flag);
    dim3 grid(Ndim / 16, Mdim / 16);
    gemm_fallback_kernel<<<grid, 256, 0, stream>>>(x, w, mask, flag, out);
  }
}

// Round 5
// 744.721 us; speedup vs baseline: 1.0694x; 1.0694x over previous
//
#include <hip/hip_runtime.h>
#include <stdint.h>

// SparseLinear: out[m][n] = sum_k x[m][k] * W[n][k] * mask[n][k]
// M = B*S = 8192, N = 4096, K = 4096, fp32 in/out, bf16-tolerance check.
// R4: LDS-free GEMM. cvt pre-passes write x/W into a TILED PANEL layout so
// MFMA fragments are lane-contiguous global dwordx4 loads (global->VGPR,
// no LDS round-trip, no barriers). R2/R3 showed LDS BW (96 KB per
// block-K-tile at 128 B/cyc/CU ~ 50% of wall) + conflicts + barrier drain
// were the bottleneck; staging scatter killed R3. Register ping-pong
// prefetch hides L2 latency (~200-400 cyc) under 16 MFMAs per K-tile.
//
// Panel layout (per 128-row tile rt, per 64-elem K-tile kt):
//   chunk index c in [0,1024): panel r=c>>8, slot=c&255,
//   holds row rt*128 + r*32 + (slot&31), elems kt*64 + (slot>>5)*8 .. +8.
//   ws addr = ((rt*64 + kt)*1024 + c) * 16 bytes.
// Wave (wr,wc) fragment (i,s,kg): addr = base + kt*16K + (wr*2+i)*4K + s*1K
//   + lane*16  -> consecutive lanes contiguous: perfect coalescing.

static constexpr int Mdim = 8192;
static constexpr int Ndim = 4096;
static constexpr int Kdim = 4096;
static constexpr int BM = 128;
static constexpr int BN = 128;

typedef __attribute__((ext_vector_type(8))) short short8;
typedef __attribute__((ext_vector_type(4))) short short4v;
typedef __attribute__((ext_vector_type(4))) float float4v;
typedef __attribute__((ext_vector_type(16))) float float16v;
typedef __attribute__((ext_vector_type(4))) int int4v;
typedef __attribute__((ext_vector_type(8))) unsigned short ushort8;

__device__ __forceinline__ unsigned short f32_to_bf16(float f) {
  union { float f; uint32_t u; } c; c.f = f;
  uint32_t u = c.u;
  u += 0x7fffu + ((u >> 16) & 1u);   // round-to-nearest-even (no NaNs in data)
  return (unsigned short)(u >> 16);
}

// ---------------------------------------------------------------------------
// Mask element-width detection. numpy bool_ = 1 byte; int32/float32 promotion
// zeroes byte positions ==1 (mod 4). 64K probes at 10% density: P(miss)~0.
// ---------------------------------------------------------------------------
__global__ void detect_mask_kernel(const unsigned char* __restrict__ m, int* __restrict__ flag) {
  __shared__ int s;
  if (threadIdx.x == 0) s = 0;
  __syncthreads();
  int found = 0;
  for (int p = threadIdx.x; p < 65536; p += blockDim.x)
    found |= (m[4 * p + 1] != 0);
  if (found) atomicOr(&s, 1);
  __syncthreads();
  if (threadIdx.x == 0) *flag = s;
}

// ---------------------------------------------------------------------------
// x fp32 -> bf16 tiled-panel transpose. One block per (rt, kt) 16 KB tile.
// Phase 1: coalesced reads (4 rows x 256 B per wave-instr) -> LDS row-major.
// Phase 2: LDS 16 B gathers (2-way worst, free) -> contiguous global writes.
// LDS row stride 68 ushorts (136 B) decorrelates row banks (32-bank stride).
// ---------------------------------------------------------------------------
__global__ __launch_bounds__(256) void cvt_x_t(const float* __restrict__ x,
                                               unsigned short* __restrict__ o) {
  __shared__ unsigned short lds[128 * 68];
  const int rt = blockIdx.x >> 6;
  const int kt = blockIdx.x & 63;
  const int t = threadIdx.x;
  const int row16 = t >> 4;   // 0..15
  const int ch = t & 15;      // 16B chunk (4 floats) within the 256 B row-seg
#pragma unroll
  for (int it = 0; it < 8; ++it) {
    const int row = it * 16 + row16;
    const float4v v = *(const float4v*)(x + (long)(rt * 128 + row) * Kdim + kt * 64 + ch * 4);
    short4v r;
#pragma unroll
    for (int j = 0; j < 4; ++j) r[j] = (short)f32_to_bf16(v[j]);
    *(short4v*)(lds + row * 68 + ch * 4) = r;
  }
  __syncthreads();
  unsigned short* ob = o + ((long)(rt * 64 + kt) * 1024) * 8;
#pragma unroll
  for (int i = 0; i < 4; ++i) {
    const int row = i * 32 + (t & 31);
    const int ch8 = t >> 5;
    const unsigned short* src = lds + row * 68 + ch8 * 8;
    ushort8 v;
#pragma unroll
    for (int j = 0; j < 8; ++j) v[j] = src[j];
    *(ushort8*)(ob + (i * 256 + t) * 8) = v;
  }
}

// W fp32 * mask -> bf16 tiled-panel transpose; mask layout chosen by *flag.
__global__ __launch_bounds__(256) void cvt_w_t(const float* __restrict__ w,
                                               const unsigned char* __restrict__ mraw,
                                               const int* __restrict__ flag,
                                               unsigned short* __restrict__ o) {
  __shared__ unsigned short lds[128 * 68];
  const int nt = blockIdx.x >> 6;
  const int kt = blockIdx.x & 63;
  const int t = threadIdx.x;
  const int row16 = t >> 4;
  const int ch = t & 15;
  const int byteLayout = *flag;
#pragma unroll
  for (int it = 0; it < 8; ++it) {
    const int row = it * 16 + row16;
    const long base = (long)(nt * 128 + row) * Kdim + kt * 64 + ch * 4;
    const float4v v = *(const float4v*)(w + base);
    int m[4];
    if (byteLayout) {
      uint32_t mb = *(const uint32_t*)(mraw + base);
#pragma unroll
      for (int j = 0; j < 4; ++j) m[j] = ((mb >> (8 * j)) & 0xffu) != 0;
    } else {
      int4v mv = *(const int4v*)((const int*)mraw + base);
#pragma unroll
      for (int j = 0; j < 4; ++j) m[j] = mv[j] != 0;
    }
    short4v r;
#pragma unroll
    for (int j = 0; j < 4; ++j) r[j] = (short)f32_to_bf16(m[j] ? v[j] : 0.0f);
    *(short4v*)(lds + row * 68 + ch * 4) = r;
  }
  __syncthreads();
  unsigned short* ob = o + ((long)(nt * 64 + kt) * 1024) * 8;
#pragma unroll
  for (int i = 0; i < 4; ++i) {
    const int row = i * 32 + (t & 31);
    const int ch8 = t >> 5;
    const unsigned short* src = lds + row * 68 + ch8 * 8;
    ushort8 v;
#pragma unroll
    for (int j = 0; j < 8; ++j) v[j] = src[j];
    *(ushort8*)(ob + (i * 256 + t) * 8) = v;
  }
}

// ---------------------------------------------------------------------------
// LDS-free bf16 MFMA GEMM on tiled-panel inputs. 256 threads = 4 waves in
// 2x2; each wave computes 64x64 as 2x2 of 32x32x16, loading its fragments
// directly global->VGPR (lane-contiguous dwordx4). No barriers. Register
// ping-pong prefetch of K-tile kt+1 during the 16 MFMAs of kt.
// C/D layout (m74/m101): col = lane&31, row = (reg&3)+8*(reg>>2)+4*(lane>>5).
// ---------------------------------------------------------------------------
__global__ __launch_bounds__(256) void gemm_direct_kernel(const unsigned short* __restrict__ X,
                                                          const unsigned short* __restrict__ W,
                                                          float* __restrict__ O) {
  const int tid = threadIdx.x;
  const int lane = tid & 63;
  const int wave = tid >> 6;
  const int wr = wave >> 1;
  const int wc = wave & 1;

  const int tm = blockIdx.x >> 5;      // tn-inner: 32 consecutive blocks share xb tile
  const int tn = blockIdx.x & 31;

  // Per-wave fragment base pointers (elems): tile base + panel wr*2 + lane*8
  const unsigned short* xp = X + (long)tm * 64 * 8192 + (wr * 2) * 2048 + lane * 8;
  const unsigned short* wp = W + (long)tn * 64 * 8192 + (wc * 2) * 2048 + lane * 8;

  float16v acc[2][2];
#pragma unroll
  for (int i = 0; i < 2; ++i)
#pragma unroll
    for (int j = 0; j < 2; ++j)
#pragma unroll
      for (int r = 0; r < 16; ++r) acc[i][j][r] = 0.f;

  short8 a[2][2][4], b[2][2][4];  // [parity][i][s]

  // Preload kt = 0
#pragma unroll
  for (int i = 0; i < 2; ++i)
#pragma unroll
    for (int s = 0; s < 4; ++s) {
      a[0][i][s] = *(const short8*)(xp + i * 2048 + s * 512);
      b[0][i][s] = *(const short8*)(wp + i * 2048 + s * 512);
    }

#pragma unroll 2
  for (int kt = 0; kt < 64; ++kt) {
    const int cur = kt & 1, nxt = cur ^ 1;
    if (kt < 63) {
      const unsigned short* xn = xp + (kt + 1) * 8192;
      const unsigned short* wn = wp + (kt + 1) * 8192;
#pragma unroll
      for (int i = 0; i < 2; ++i)
#pragma unroll
        for (int s = 0; s < 4; ++s) {
          a[nxt][i][s] = *(const short8*)(xn + i * 2048 + s * 512);
          b[nxt][i][s] = *(const short8*)(wn + i * 2048 + s * 512);
        }
    }
#pragma unroll
    for (int s = 0; s < 4; ++s)
#pragma unroll
      for (int i = 0; i < 2; ++i)
#pragma unroll
        for (int j = 0; j < 2; ++j)
          acc[i][j] = __builtin_amdgcn_mfma_f32_32x32x16_bf16(a[cur][i][s], b[cur][j][s],
                                                              acc[i][j], 0, 0, 0);
  }

  const int ml = lane & 31;
  const int kg = lane >> 5;
  const int row0 = tm * BM;
  const int col0 = tn * BN;
#pragma unroll
  for (int i = 0; i < 2; ++i) {
#pragma unroll
    for (int j = 0; j < 2; ++j) {
      const long rbase = row0 + wr * 64 + i * 32;
      const long cg = col0 + wc * 64 + j * 32 + ml;
#pragma unroll
      for (int reg = 0; reg < 16; ++reg) {
        const long row = rbase + (reg & 3) + 8 * (reg >> 2) + 4 * kg;
        O[row * (long)Ndim + cg] = acc[i][j][reg];
      }
    }
  }
}

// ---------------------------------------------------------------------------
// Fallback (only if ws too small for bf16 staging): fp32 LDS-tiled GEMM.
// ---------------------------------------------------------------------------
__global__ void gemm_fallback_kernel(const float* __restrict__ X, const float* __restrict__ Wt,
                                     const unsigned char* __restrict__ mraw,
                                     const int* __restrict__ flag, float* __restrict__ O) {
  __shared__ float sX[16][17];
  __shared__ float sW[16][17];
  const int tx = threadIdx.x & 15;
  const int ty = threadIdx.x >> 4;
  const long row = blockIdx.y * 16 + ty;
  const long colblock = blockIdx.x * 16;
  const int byteLayout = *flag;
  float acc = 0.f;
  for (int k0 = 0; k0 < Kdim; k0 += 16) {
    sX[ty][tx] = X[row * Kdim + k0 + tx];
    const long wi = (colblock + ty) * (long)Kdim + k0 + tx;
    const int mv = byteLayout ? (mraw[wi] != 0) : (((const int*)mraw)[wi] != 0);
    sW[ty][tx] = mv ? Wt[wi] : 0.f;
    __syncthreads();
#pragma unroll
    for (int k = 0; k < 16; ++k) acc += sX[ty][k] * sW[tx][k];
    __syncthreads();
  }
  O[row * Ndim + colblock + tx] = acc;
}

extern "C" void kernel_launch(void* const* d_in, const int* in_sizes, int n_in,
                              void* d_out, int out_size, void* d_ws, size_t ws_size,
                              hipStream_t stream) {
  const float* x = (const float*)d_in[0];               // [8192, 4096] fp32
  const float* w = (const float*)d_in[1];               // [4096, 4096] fp32
  const unsigned char* mask = (const unsigned char*)d_in[2];  // bool (layout detected)
  float* out = (float*)d_out;                           // [8192, 4096] fp32

  const size_t xb_off = 0;
  const size_t wb_off = (size_t)Mdim * Kdim * 2;             // 67,108,864
  const size_t flag_off = wb_off + (size_t)Ndim * Kdim * 2;  // 100,663,296
  const size_t needed = flag_off + 16;

  if (ws_size >= needed) {
    unsigned short* xb = (unsigned short*)((char*)d_ws + xb_off);
    unsigned short* wb = (unsigned short*)((char*)d_ws + wb_off);
    int* flag = (int*)((char*)d_ws + flag_off);

    detect_mask_kernel<<<1, 1024, 0, stream>>>(mask, flag);
    cvt_x_t<<<(Mdim / 128) * (Kdim / 64), 256, 0, stream>>>(x, xb);
    cvt_w_t<<<(Ndim / 128) * (Kdim / 64), 256, 0, stream>>>(w, mask, flag, wb);
    gemm_direct_kernel<<<(Mdim / BM) * (Ndim / BN), 256, 0, stream>>>(xb, wb, out);
  } else {
    int* flag = (int*)d_ws;
    detect_mask_kernel<<<1, 1024, 0, stream>>>(mask, flag);
    dim3 grid(Ndim / 16, Mdim / 16);
    gemm_fallback_kernel<<<grid, 256, 0, stream>>>(x, w, mask, flag, out);
  }
}